// Round 1
// baseline (268.609 us; speedup 1.0000x reference)
//
#include <hip/hip_runtime.h>
#include <math.h>

#define BB   32
#define HH   56
#define WWI  56
#define CC   256
#define LL   3136      // H*W
#define SS   16
#define NCH  56        // chunks per batch (one per image row)
#define CHL  56        // chunk length
#define EPSV 1e-5f

// -------------------- K0: zero BN accumulators --------------------
__global__ void k_zero(float* __restrict__ p) {
    p[threadIdx.x] = 0.f;   // 512 threads cover bnsum(256)+bnsq(256)
}

// -------------------- K1: per-(b,slice) spatial partial sum/max over C ----
// grid (32,8), block 256 (4 waves). wave w handles positions p = sl*392 + 4k + w.
// thread lane l owns channels 4l..4l+3 (float4). Coalesced 1KB/wave/iter.
__global__ void k_ca_partial(const float* __restrict__ x,
                             float* __restrict__ psum, float* __restrict__ pmax) {
    const int b = blockIdx.x, sl = blockIdx.y;
    const int wv = threadIdx.x >> 6, l = threadIdx.x & 63;
    const float4* x4 = (const float4*)x;
    const size_t base = (size_t)b * LL * 64;
    float4 s  = make_float4(0.f, 0.f, 0.f, 0.f);
    float4 mx = make_float4(-1e30f, -1e30f, -1e30f, -1e30f);
    for (int k = 0; k < 98; k++) {
        int p = sl * 392 + k * 4 + wv;
        float4 v = x4[base + (size_t)p * 64 + l];
        s.x += v.x; s.y += v.y; s.z += v.z; s.w += v.w;
        mx.x = fmaxf(mx.x, v.x); mx.y = fmaxf(mx.y, v.y);
        mx.z = fmaxf(mx.z, v.z); mx.w = fmaxf(mx.w, v.w);
    }
    const int sub = (b * 8 + sl) * 4 + wv;   // 32 sub-slices per batch
    ((float4*)psum)[sub * 64 + l] = s;
    ((float4*)pmax)[sub * 64 + l] = mx;
}

// -------------------- K2: combine partials + ChannelAttention FC ----------
// grid 32, block 256. gate[b][c] = sigmoid(fc(avg)+fc(max))
__global__ void k_ca_fc(const float* __restrict__ psum, const float* __restrict__ pmax,
                        const float* __restrict__ w1, const float* __restrict__ w2,
                        float* __restrict__ gate) {
    const int b = blockIdx.x, tid = threadIdx.x;
    __shared__ float avg[CC], mxs[CC], hsum[16];
    float s = 0.f, mx = -1e30f;
    for (int k = 0; k < 32; k++) {
        s += psum[(b * 32 + k) * CC + tid];
        mx = fmaxf(mx, pmax[(b * 32 + k) * CC + tid]);
    }
    avg[tid] = s * (1.f / 3136.f);
    mxs[tid] = mx;
    __syncthreads();
    // h1[r] = relu(sum_c v[c]*w1[r,c]); 16 threads per row r, 16 channels each.
    const int r = tid >> 4, l = tid & 15;
    float pa = 0.f, pm = 0.f;
    for (int j = 0; j < 16; j++) {
        float w = w1[r * CC + l * 16 + j];
        pa += avg[l * 16 + j] * w;
        pm += mxs[l * 16 + j] * w;
    }
#pragma unroll
    for (int d = 1; d < 16; d <<= 1) { pa += __shfl_xor(pa, d); pm += __shfl_xor(pm, d); }
    if (l == 0) hsum[r] = fmaxf(pa, 0.f) + fmaxf(pm, 0.f);
    __syncthreads();
    float o = 0.f;
#pragma unroll
    for (int r2 = 0; r2 < 16; r2++) o += hsum[r2] * w2[tid * 16 + r2];
    gate[b * CC + tid] = 1.f / (1.f + __expf(-o));
}

// -------------------- K3: per-position channel mean/max of xc -------------
// one wave per position; lane l loads float4 at c=4l. grid 25088, block 256.
__global__ void k_pos_reduce(const float* __restrict__ x, const float* __restrict__ gate,
                             float* __restrict__ m, float* __restrict__ cmax) {
    const int wv = threadIdx.x >> 6, l = threadIdx.x & 63;
    const int pos = blockIdx.x * 4 + wv;           // 0..100351 == b*3136+t
    const int b = pos / LL;
    float4 v = ((const float4*)x)[(size_t)pos * 64 + l];
    float4 g = ((const float4*)gate)[b * 64 + l];
    v.x *= g.x; v.y *= g.y; v.z *= g.z; v.w *= g.w;
    float s  = v.x + v.y + v.z + v.w;
    float mm = fmaxf(fmaxf(v.x, v.y), fmaxf(v.z, v.w));
#pragma unroll
    for (int d = 1; d < 64; d <<= 1) {
        s += __shfl_xor(s, d);
        mm = fmaxf(mm, __shfl_xor(mm, d));
    }
    if (l == 0) { m[pos] = s * (1.f / 256.f); cmax[pos] = mm; }
}

__device__ __forceinline__ float softplusf(float z) {
    return fmaxf(z, 0.f) + log1pf(__expf(-fabsf(z)));
}

// -------------------- K4: scan phase 1 — per-chunk (P,Q) ------------------
// 16-lane group per (b,chunk); 1792 groups -> 112 blocks of 256.
__global__ void k_scan1(const float* __restrict__ m,
                        const float* __restrict__ dw, const float* __restrict__ db,
                        const float* __restrict__ Bw, const float* __restrict__ Bb,
                        const float* __restrict__ A,
                        float* __restrict__ Pp, float* __restrict__ Qq) {
    __shared__ float mlds[16 * 57];
    const int tid = threadIdx.x;
    const int gbase = blockIdx.x * 16;
    for (int i = tid; i < 16 * CHL; i += 256) {
        int g = i / CHL, t = i - g * CHL;
        int gid = gbase + g;
        int b = gid / NCH, ch = gid - b * NCH;
        mlds[g * 57 + t] = m[b * LL + ch * CHL + t];
    }
    __syncthreads();
    const int g = tid >> 4, s = tid & 15;
    const int gid = gbase + g;
    const int b = gid / NCH, ch = gid - b * NCH;
    const float dwv = dw[0], dbv = db[0];
    const float As = A[s], Bws = Bw[s], Bbs = Bb[s];
    float P = 1.f, Q = 0.f;
    for (int t = 0; t < CHL; t++) {
        float mv = mlds[g * 57 + t];
        float delta = softplusf(mv * dwv + dbv);
        float a  = __expf(delta * As);
        float bb = delta * mv * (mv * Bws + Bbs);
        Q = a * Q + bb;
        P *= a;
    }
    const int idx = ch * 512 + b * 16 + s;   // layout [chunk][b][s] for K5 coalescing
    Pp[idx] = P; Qq[idx] = Q;
}

// -------------------- K5: scan phase 2 — combine chunk prefixes -----------
// 1 block of 512; lane = (b,s); 56 sequential chunk steps; loads coalesced.
__global__ void k_scan2(const float* __restrict__ Pp, const float* __restrict__ Qq,
                        float* __restrict__ hst) {
    const int tid = threadIdx.x;  // b*16+s
    float h = 0.f;
    for (int k = 0; k < NCH; k++) {
        int idx = k * 512 + tid;
        hst[idx] = h;              // state entering chunk k
        h = Pp[idx] * h + Qq[idx];
    }
}

// -------------------- K6: scan phase 3 — emit sigmoid(y) ------------------
__global__ void k_scan3(const float* __restrict__ m, const float* __restrict__ hst,
                        const float* __restrict__ dw, const float* __restrict__ db,
                        const float* __restrict__ Bw, const float* __restrict__ Bb,
                        const float* __restrict__ Cw, const float* __restrict__ Cb,
                        const float* __restrict__ A,
                        float* __restrict__ sy) {
    __shared__ float mlds[16 * 57];
    const int tid = threadIdx.x;
    const int gbase = blockIdx.x * 16;
    for (int i = tid; i < 16 * CHL; i += 256) {
        int g = i / CHL, t = i - g * CHL;
        int gid = gbase + g;
        int b = gid / NCH, ch = gid - b * NCH;
        mlds[g * 57 + t] = m[b * LL + ch * CHL + t];
    }
    __syncthreads();
    const int g = tid >> 4, s = tid & 15;
    const int gid = gbase + g;
    const int b = gid / NCH, ch = gid - b * NCH;
    const float dwv = dw[0], dbv = db[0];
    const float As = A[s], Bws = Bw[s], Bbs = Bb[s];
    const float Cws = Cw[s], Cbs = Cb[s];
    float h = hst[ch * 512 + b * 16 + s];
    for (int t = 0; t < CHL; t++) {
        float mv = mlds[g * 57 + t];
        float delta = softplusf(mv * dwv + dbv);
        float a  = __expf(delta * As);
        float bb = delta * mv * (mv * Bws + Bbs);
        float c  = mv * Cws + Cbs;
        h = a * h + bb;
        float p = h * c;
#pragma unroll
        for (int d = 1; d < 16; d <<= 1) p += __shfl_xor(p, d);
        if (s == 0) sy[b * LL + ch * CHL + t] = 1.f / (1.f + __expf(-p));
    }
}

// -------------------- K7: LSA 7x7 conv + sigmoid --------------------------
// grid (32,56), block 64; thread = output column.
__global__ void k_lsa(const float* __restrict__ m, const float* __restrict__ cmax,
                      const float* __restrict__ wc, float* __restrict__ ssg) {
    __shared__ float w[98];
    const int b = blockIdx.x, h = blockIdx.y, tid = threadIdx.x;
    for (int i = tid; i < 98; i += 64) w[i] = wc[i];
    __syncthreads();
    if (tid >= WWI) return;
    float acc = 0.f;
    for (int kh = 0; kh < 7; kh++) {
        int hh = h + kh - 3;
        if ((unsigned)hh >= (unsigned)HH) continue;
        const int rb = b * LL + hh * WWI;
        for (int kw = 0; kw < 7; kw++) {
            int ww = tid + kw - 3;
            if ((unsigned)ww >= (unsigned)WWI) continue;
            acc += m[rb + ww] * w[(kh * 7 + kw) * 2] + cmax[rb + ww] * w[(kh * 7 + kw) * 2 + 1];
        }
    }
    ssg[b * LL + h * WWI + tid] = 1.f / (1.f + __expf(-acc));
}

// -------------------- K8: BN stats (sum, sumsq per channel) ---------------
// grid (32,8), block 256; same access pattern as K1; x2 recomputed on the fly.
__global__ void k_bnstat(const float* __restrict__ x, const float* __restrict__ gate,
                         const float* __restrict__ sy, const float* __restrict__ ssg,
                         float* __restrict__ bnsum, float* __restrict__ bnsq) {
    const int b = blockIdx.x, sl = blockIdx.y;
    const int wv = threadIdx.x >> 6, l = threadIdx.x & 63;
    const float4* x4 = (const float4*)x;
    float4 g = ((const float4*)gate)[b * 64 + l];
    float4 s = make_float4(0.f, 0.f, 0.f, 0.f);
    float4 q = make_float4(0.f, 0.f, 0.f, 0.f);
    for (int k = 0; k < 98; k++) {
        int p = sl * 392 + k * 4 + wv;
        int pos = b * LL + p;
        float4 v = x4[(size_t)pos * 64 + l];
        float g2 = sy[pos] + ssg[pos];
        float fx = v.x * g.x * g2, fy = v.y * g.y * g2, fz = v.z * g.z * g2, fw = v.w * g.w * g2;
        s.x += fx; s.y += fy; s.z += fz; s.w += fw;
        q.x += fx * fx; q.y += fy * fy; q.z += fz * fz; q.w += fw * fw;
    }
    atomicAdd(&bnsum[l * 4 + 0], s.x); atomicAdd(&bnsum[l * 4 + 1], s.y);
    atomicAdd(&bnsum[l * 4 + 2], s.z); atomicAdd(&bnsum[l * 4 + 3], s.w);
    atomicAdd(&bnsq [l * 4 + 0], q.x); atomicAdd(&bnsq [l * 4 + 1], q.y);
    atomicAdd(&bnsq [l * 4 + 2], q.z); atomicAdd(&bnsq [l * 4 + 3], q.w);
}

// -------------------- K9: BN finalize -> per-channel scale/shift ----------
__global__ void k_bnfin(const float* __restrict__ bnsum, const float* __restrict__ bnsq,
                        const float* __restrict__ gamma, const float* __restrict__ beta,
                        float* __restrict__ sc, float* __restrict__ sh) {
    const int c = threadIdx.x;
    const float inv = 1.f / (float)(BB * LL);
    float mean = bnsum[c] * inv;
    float var  = bnsq[c] * inv - mean * mean;
    float s = gamma[c] * rsqrtf(var + EPSV);
    sc[c] = s;
    sh[c] = beta[c] - mean * s;
}

// -------------------- K10: normalize + ReLU + write -----------------------
// grid-stride over 6,422,528 float4s; one wave covers exactly one position.
__global__ void k_final(const float* __restrict__ x, const float* __restrict__ gate,
                        const float* __restrict__ sy, const float* __restrict__ ssg,
                        const float* __restrict__ sc, const float* __restrict__ sh,
                        float* __restrict__ out) {
    const int l = threadIdx.x & 63;
    const float4 scv = ((const float4*)sc)[l];
    const float4 shv = ((const float4*)sh)[l];
    const size_t total = (size_t)BB * LL * 64;
    for (size_t i = blockIdx.x * (size_t)blockDim.x + threadIdx.x; i < total;
         i += (size_t)gridDim.x * blockDim.x) {
        size_t pos = i >> 6;
        int b = (int)(pos / LL);
        float4 v = ((const float4*)x)[i];
        float4 g = ((const float4*)gate)[b * 64 + l];
        float g2 = sy[pos] + ssg[pos];
        float4 o;
        o.x = fmaxf(v.x * g.x * g2 * scv.x + shv.x, 0.f);
        o.y = fmaxf(v.y * g.y * g2 * scv.y + shv.y, 0.f);
        o.z = fmaxf(v.z * g.z * g2 * scv.z + shv.z, 0.f);
        o.w = fmaxf(v.w * g.w * g2 * scv.w + shv.w, 0.f);
        ((float4*)out)[i] = o;
    }
}

extern "C" void kernel_launch(void* const* d_in, const int* in_sizes, int n_in,
                              void* d_out, int out_size, void* d_ws, size_t ws_size,
                              hipStream_t stream) {
    const float* x     = (const float*)d_in[0];
    const float* ca_w1 = (const float*)d_in[1];
    const float* ca_w2 = (const float*)d_in[2];
    const float* lsa_w = (const float*)d_in[3];
    const float* A     = (const float*)d_in[4];
    const float* d_wp  = (const float*)d_in[5];
    const float* d_bp  = (const float*)d_in[6];
    const float* B_wp  = (const float*)d_in[7];
    const float* B_bp  = (const float*)d_in[8];
    const float* C_wp  = (const float*)d_in[9];
    const float* C_bp  = (const float*)d_in[10];
    const float* bn_g  = (const float*)d_in[11];
    const float* bn_b  = (const float*)d_in[12];
    float* out = (float*)d_out;

    float* ws    = (float*)d_ws;
    float* gate  = ws;                 // 8192
    float* psum  = gate  + 8192;       // 262144
    float* pmax  = psum  + 262144;     // 262144
    float* m     = pmax  + 262144;     // 100352
    float* cmax  = m     + 100352;     // 100352
    float* sy    = cmax  + 100352;     // 100352
    float* ssg   = sy    + 100352;     // 100352
    float* Pp    = ssg   + 100352;     // 28672
    float* Qq    = Pp    + 28672;      // 28672
    float* hst   = Qq    + 28672;      // 28672
    float* bnsum = hst   + 28672;      // 256
    float* bnsq  = bnsum + 256;        // 256
    float* scv   = bnsq  + 256;        // 256
    float* shv   = scv   + 256;        // 256

    k_zero<<<1, 512, 0, stream>>>(bnsum);                       // zeros bnsum+bnsq
    k_ca_partial<<<dim3(BB, 8), 256, 0, stream>>>(x, psum, pmax);
    k_ca_fc<<<BB, 256, 0, stream>>>(psum, pmax, ca_w1, ca_w2, gate);
    k_pos_reduce<<<BB * LL / 4, 256, 0, stream>>>(x, gate, m, cmax);
    k_scan1<<<112, 256, 0, stream>>>(m, d_wp, d_bp, B_wp, B_bp, A, Pp, Qq);
    k_scan2<<<1, 512, 0, stream>>>(Pp, Qq, hst);
    k_scan3<<<112, 256, 0, stream>>>(m, hst, d_wp, d_bp, B_wp, B_bp, C_wp, C_bp, A, sy);
    k_lsa<<<dim3(BB, HH), 64, 0, stream>>>(m, cmax, lsa_w, ssg);
    k_bnstat<<<dim3(BB, 8), 256, 0, stream>>>(x, gate, sy, ssg, bnsum, bnsq);
    k_bnfin<<<1, 256, 0, stream>>>(bnsum, bnsq, bn_g, bn_b, scv, shv);
    k_final<<<4096, 256, 0, stream>>>(x, gate, sy, ssg, scv, shv, out);
}

// Round 2
// 174.558 us; speedup vs baseline: 1.5388x; 1.5388x over previous
//
#include <hip/hip_runtime.h>
#include <math.h>

#define BB   32
#define HH   56
#define WWI  56
#define CC   256
#define LL   3136      // H*W
#define SS   16
#define NCH  56        // chunks per batch (one per image row)
#define CHL  56        // chunk length
#define NSL  98        // spatial slices for reductions (32 positions each)
#define EPSV 1e-5f

// -------------------- K1: per-(b,slice) spatial partial sum/max over C ----
// grid (32,98), block 256 (4 waves). wave wv handles positions sl*32 + 4k + wv.
// lane l owns channels 4l..4l+3 (float4). LDS combine across waves -> 1 partial/block.
__global__ void k_ca_partial(const float* __restrict__ x,
                             float* __restrict__ psum, float* __restrict__ pmax) {
    const int b = blockIdx.x, sl = blockIdx.y;
    const int wv = threadIdx.x >> 6, l = threadIdx.x & 63;
    const float4* x4 = (const float4*)x;
    const size_t base = ((size_t)b * LL + sl * 32) * 64;
    float4 s  = make_float4(0.f, 0.f, 0.f, 0.f);
    float4 mx = make_float4(-1e30f, -1e30f, -1e30f, -1e30f);
#pragma unroll
    for (int k = 0; k < 8; k++) {
        float4 v = x4[base + (size_t)(k * 4 + wv) * 64 + l];
        s.x += v.x; s.y += v.y; s.z += v.z; s.w += v.w;
        mx.x = fmaxf(mx.x, v.x); mx.y = fmaxf(mx.y, v.y);
        mx.z = fmaxf(mx.z, v.z); mx.w = fmaxf(mx.w, v.w);
    }
    __shared__ float4 ls[4][64], lm[4][64];
    ls[wv][l] = s; lm[wv][l] = mx;
    __syncthreads();
    if (wv == 0) {
#pragma unroll
        for (int w = 1; w < 4; w++) {
            float4 a = ls[w][l], m2 = lm[w][l];
            s.x += a.x; s.y += a.y; s.z += a.z; s.w += a.w;
            mx.x = fmaxf(mx.x, m2.x); mx.y = fmaxf(mx.y, m2.y);
            mx.z = fmaxf(mx.z, m2.z); mx.w = fmaxf(mx.w, m2.w);
        }
        ((float4*)psum)[(b * NSL + sl) * 64 + l] = s;
        ((float4*)pmax)[(b * NSL + sl) * 64 + l] = mx;
    }
}

// -------------------- K2: combine partials + ChannelAttention FC ----------
__global__ void k_ca_fc(const float* __restrict__ psum, const float* __restrict__ pmax,
                        const float* __restrict__ w1, const float* __restrict__ w2,
                        float* __restrict__ gate) {
    const int b = blockIdx.x, tid = threadIdx.x;
    __shared__ float avg[CC], mxs[CC], hsum[16];
    float s = 0.f, mx = -1e30f;
    for (int k = 0; k < NSL; k++) {
        s += psum[(b * NSL + k) * CC + tid];
        mx = fmaxf(mx, pmax[(b * NSL + k) * CC + tid]);
    }
    avg[tid] = s * (1.f / 3136.f);
    mxs[tid] = mx;
    __syncthreads();
    const int r = tid >> 4, l = tid & 15;
    float pa = 0.f, pm = 0.f;
    for (int j = 0; j < 16; j++) {
        float w = w1[r * CC + l * 16 + j];
        pa += avg[l * 16 + j] * w;
        pm += mxs[l * 16 + j] * w;
    }
#pragma unroll
    for (int d = 1; d < 16; d <<= 1) { pa += __shfl_xor(pa, d); pm += __shfl_xor(pm, d); }
    if (l == 0) hsum[r] = fmaxf(pa, 0.f) + fmaxf(pm, 0.f);
    __syncthreads();
    float o = 0.f;
#pragma unroll
    for (int r2 = 0; r2 < 16; r2++) o += hsum[r2] * w2[tid * 16 + r2];
    gate[b * CC + tid] = 1.f / (1.f + __expf(-o));
}

// -------------------- K3: per-position channel mean/max of xc -------------
__global__ void k_pos_reduce(const float* __restrict__ x, const float* __restrict__ gate,
                             float* __restrict__ m, float* __restrict__ cmax) {
    const int wv = threadIdx.x >> 6, l = threadIdx.x & 63;
    const int pos = blockIdx.x * 4 + wv;           // b*3136+t
    const int b = pos / LL;
    float4 v = ((const float4*)x)[(size_t)pos * 64 + l];
    float4 g = ((const float4*)gate)[b * 64 + l];
    v.x *= g.x; v.y *= g.y; v.z *= g.z; v.w *= g.w;
    float s  = v.x + v.y + v.z + v.w;
    float mm = fmaxf(fmaxf(v.x, v.y), fmaxf(v.z, v.w));
#pragma unroll
    for (int d = 1; d < 64; d <<= 1) {
        s += __shfl_xor(s, d);
        mm = fmaxf(mm, __shfl_xor(mm, d));
    }
    if (l == 0) { m[pos] = s * (1.f / 256.f); cmax[pos] = mm; }
}

__device__ __forceinline__ float softplusf(float z) {
    return fmaxf(z, 0.f) + log1pf(__expf(-fabsf(z)));
}

// -------------------- K4: scan phase 1 — per-chunk (P,Q) ------------------
__global__ void k_scan1(const float* __restrict__ m,
                        const float* __restrict__ dw, const float* __restrict__ db,
                        const float* __restrict__ Bw, const float* __restrict__ Bb,
                        const float* __restrict__ A,
                        float* __restrict__ Pp, float* __restrict__ Qq) {
    __shared__ float mlds[16 * 57];
    const int tid = threadIdx.x;
    const int gbase = blockIdx.x * 16;
    for (int i = tid; i < 16 * CHL; i += 256) {
        int g = i / CHL, t = i - g * CHL;
        int gid = gbase + g;
        int b = gid / NCH, ch = gid - b * NCH;
        mlds[g * 57 + t] = m[b * LL + ch * CHL + t];
    }
    __syncthreads();
    const int g = tid >> 4, s = tid & 15;
    const int gid = gbase + g;
    const int b = gid / NCH, ch = gid - b * NCH;
    const float dwv = dw[0], dbv = db[0];
    const float As = A[s], Bws = Bw[s], Bbs = Bb[s];
    float P = 1.f, Q = 0.f;
    for (int t = 0; t < CHL; t++) {
        float mv = mlds[g * 57 + t];
        float delta = softplusf(mv * dwv + dbv);
        float a  = __expf(delta * As);
        float bb = delta * mv * (mv * Bws + Bbs);
        Q = a * Q + bb;
        P *= a;
    }
    const int idx = ch * 512 + b * 16 + s;
    Pp[idx] = P; Qq[idx] = Q;
}

// -------------------- K5: scan phase 2 — combine chunk prefixes -----------
__global__ void k_scan2(const float* __restrict__ Pp, const float* __restrict__ Qq,
                        float* __restrict__ hst) {
    const int tid = threadIdx.x;  // b*16+s
    float h = 0.f;
    for (int k = 0; k < NCH; k++) {
        int idx = k * 512 + tid;
        hst[idx] = h;
        h = Pp[idx] * h + Qq[idx];
    }
}

// -------------------- K6: scan phase 3 — emit sigmoid(y) ------------------
__global__ void k_scan3(const float* __restrict__ m, const float* __restrict__ hst,
                        const float* __restrict__ dw, const float* __restrict__ db,
                        const float* __restrict__ Bw, const float* __restrict__ Bb,
                        const float* __restrict__ Cw, const float* __restrict__ Cb,
                        const float* __restrict__ A,
                        float* __restrict__ sy) {
    __shared__ float mlds[16 * 57];
    const int tid = threadIdx.x;
    const int gbase = blockIdx.x * 16;
    for (int i = tid; i < 16 * CHL; i += 256) {
        int g = i / CHL, t = i - g * CHL;
        int gid = gbase + g;
        int b = gid / NCH, ch = gid - b * NCH;
        mlds[g * 57 + t] = m[b * LL + ch * CHL + t];
    }
    __syncthreads();
    const int g = tid >> 4, s = tid & 15;
    const int gid = gbase + g;
    const int b = gid / NCH, ch = gid - b * NCH;
    const float dwv = dw[0], dbv = db[0];
    const float As = A[s], Bws = Bw[s], Bbs = Bb[s];
    const float Cws = Cw[s], Cbs = Cb[s];
    float h = hst[ch * 512 + b * 16 + s];
    for (int t = 0; t < CHL; t++) {
        float mv = mlds[g * 57 + t];
        float delta = softplusf(mv * dwv + dbv);
        float a  = __expf(delta * As);
        float bb = delta * mv * (mv * Bws + Bbs);
        float c  = mv * Cws + Cbs;
        h = a * h + bb;
        float p = h * c;
#pragma unroll
        for (int d = 1; d < 16; d <<= 1) p += __shfl_xor(p, d);
        if (s == 0) sy[b * LL + ch * CHL + t] = 1.f / (1.f + __expf(-p));
    }
}

// -------------------- K7: LSA 7x7 conv + sigmoid --------------------------
__global__ void k_lsa(const float* __restrict__ m, const float* __restrict__ cmax,
                      const float* __restrict__ wc, float* __restrict__ ssg) {
    __shared__ float w[98];
    const int b = blockIdx.x, h = blockIdx.y, tid = threadIdx.x;
    for (int i = tid; i < 98; i += 64) w[i] = wc[i];
    __syncthreads();
    if (tid >= WWI) return;
    float acc = 0.f;
    for (int kh = 0; kh < 7; kh++) {
        int hh = h + kh - 3;
        if ((unsigned)hh >= (unsigned)HH) continue;
        const int rb = b * LL + hh * WWI;
        for (int kw = 0; kw < 7; kw++) {
            int ww = tid + kw - 3;
            if ((unsigned)ww >= (unsigned)WWI) continue;
            acc += m[rb + ww] * w[(kh * 7 + kw) * 2] + cmax[rb + ww] * w[(kh * 7 + kw) * 2 + 1];
        }
    }
    ssg[b * LL + h * WWI + tid] = 1.f / (1.f + __expf(-acc));
}

// -------------------- K8: BN partial stats per (b,slice) ------------------
// grid (32,98), block 256; LDS combine -> pb[slice][0:256]=sum, [256:512]=sumsq
__global__ void k_bnstat(const float* __restrict__ x, const float* __restrict__ gate,
                         const float* __restrict__ sy, const float* __restrict__ ssg,
                         float* __restrict__ pb) {
    const int b = blockIdx.x, sl = blockIdx.y;
    const int wv = threadIdx.x >> 6, l = threadIdx.x & 63;
    const float4* x4 = (const float4*)x;
    float4 g = ((const float4*)gate)[b * 64 + l];
    float4 s = make_float4(0.f, 0.f, 0.f, 0.f);
    float4 q = make_float4(0.f, 0.f, 0.f, 0.f);
#pragma unroll
    for (int k = 0; k < 8; k++) {
        int pos = b * LL + sl * 32 + k * 4 + wv;
        float4 v = x4[(size_t)pos * 64 + l];
        float g2 = sy[pos] + ssg[pos];
        float fx = v.x * g.x * g2, fy = v.y * g.y * g2, fz = v.z * g.z * g2, fw = v.w * g.w * g2;
        s.x += fx; s.y += fy; s.z += fz; s.w += fw;
        q.x += fx * fx; q.y += fy * fy; q.z += fz * fz; q.w += fw * fw;
    }
    __shared__ float4 ls[4][64], lq[4][64];
    ls[wv][l] = s; lq[wv][l] = q;
    __syncthreads();
    if (wv == 0) {
#pragma unroll
        for (int w = 1; w < 4; w++) {
            float4 a = ls[w][l], c = lq[w][l];
            s.x += a.x; s.y += a.y; s.z += a.z; s.w += a.w;
            q.x += c.x; q.y += c.y; q.z += c.z; q.w += c.w;
        }
        ((float4*)pb)[(b * NSL + sl) * 128 + l] = s;
        ((float4*)pb)[(b * NSL + sl) * 128 + 64 + l] = q;
    }
}

// -------------------- K8b: reduce BN partials (3136 slices -> 512 scalars) -
__global__ void k_bnred(const float* __restrict__ pb,
                        float* __restrict__ bnsum, float* __restrict__ bnsq) {
    const int o = blockIdx.x;   // 0..511
    const int tid = threadIdx.x;
    float acc = 0.f;
    for (int sl = tid; sl < BB * NSL; sl += 256) acc += pb[(size_t)sl * 512 + o];
    __shared__ float red[256];
    red[tid] = acc;
    __syncthreads();
    for (int d = 128; d > 0; d >>= 1) {
        if (tid < d) red[tid] += red[tid + d];
        __syncthreads();
    }
    if (tid == 0) { if (o < 256) bnsum[o] = red[0]; else bnsq[o - 256] = red[0]; }
}

// -------------------- K9: BN finalize -> per-channel scale/shift ----------
__global__ void k_bnfin(const float* __restrict__ bnsum, const float* __restrict__ bnsq,
                        const float* __restrict__ gamma, const float* __restrict__ beta,
                        float* __restrict__ sc, float* __restrict__ sh) {
    const int c = threadIdx.x;
    const float inv = 1.f / (float)(BB * LL);
    float mean = bnsum[c] * inv;
    float var  = bnsq[c] * inv - mean * mean;
    float s = gamma[c] * rsqrtf(var + EPSV);
    sc[c] = s;
    sh[c] = beta[c] - mean * s;
}

// -------------------- K10: normalize + ReLU + write -----------------------
__global__ void k_final(const float* __restrict__ x, const float* __restrict__ gate,
                        const float* __restrict__ sy, const float* __restrict__ ssg,
                        const float* __restrict__ sc, const float* __restrict__ sh,
                        float* __restrict__ out) {
    const int l = threadIdx.x & 63;
    const float4 scv = ((const float4*)sc)[l];
    const float4 shv = ((const float4*)sh)[l];
    const size_t total = (size_t)BB * LL * 64;
    for (size_t i = blockIdx.x * (size_t)blockDim.x + threadIdx.x; i < total;
         i += (size_t)gridDim.x * blockDim.x) {
        size_t pos = i >> 6;
        int b = (int)(pos / LL);
        float4 v = ((const float4*)x)[i];
        float4 g = ((const float4*)gate)[b * 64 + l];
        float g2 = sy[pos] + ssg[pos];
        float4 o;
        o.x = fmaxf(v.x * g.x * g2 * scv.x + shv.x, 0.f);
        o.y = fmaxf(v.y * g.y * g2 * scv.y + shv.y, 0.f);
        o.z = fmaxf(v.z * g.z * g2 * scv.z + shv.z, 0.f);
        o.w = fmaxf(v.w * g.w * g2 * scv.w + shv.w, 0.f);
        ((float4*)out)[i] = o;
    }
}

extern "C" void kernel_launch(void* const* d_in, const int* in_sizes, int n_in,
                              void* d_out, int out_size, void* d_ws, size_t ws_size,
                              hipStream_t stream) {
    const float* x     = (const float*)d_in[0];
    const float* ca_w1 = (const float*)d_in[1];
    const float* ca_w2 = (const float*)d_in[2];
    const float* lsa_w = (const float*)d_in[3];
    const float* A     = (const float*)d_in[4];
    const float* d_wp  = (const float*)d_in[5];
    const float* d_bp  = (const float*)d_in[6];
    const float* B_wp  = (const float*)d_in[7];
    const float* B_bp  = (const float*)d_in[8];
    const float* C_wp  = (const float*)d_in[9];
    const float* C_bp  = (const float*)d_in[10];
    const float* bn_g  = (const float*)d_in[11];
    const float* bn_b  = (const float*)d_in[12];
    float* out = (float*)d_out;

    // Large partial buffers live in d_out (fully overwritten by k_final at the end).
    float* psum = out;                         // 32*98*256 = 802,816
    float* pmax = psum + BB * NSL * CC;        // 802,816
    float* pb   = pmax + BB * NSL * CC;        // 32*98*512 = 1,605,632  (total 3.2M < 25.7M)

    float* ws    = (float*)d_ws;
    float* gate  = ws;                 // 8192
    float* m     = gate  + 8192;       // 100352
    float* cmax  = m     + 100352;     // 100352
    float* sy    = cmax  + 100352;     // 100352
    float* ssg   = sy    + 100352;     // 100352
    float* Pp    = ssg   + 100352;     // 28672
    float* Qq    = Pp    + 28672;      // 28672
    float* hst   = Qq    + 28672;      // 28672
    float* bnsum = hst   + 28672;      // 256
    float* bnsq  = bnsum + 256;        // 256
    float* scv   = bnsq  + 256;        // 256
    float* shv   = scv   + 256;        // 256

    k_ca_partial<<<dim3(BB, NSL), 256, 0, stream>>>(x, psum, pmax);
    k_ca_fc<<<BB, 256, 0, stream>>>(psum, pmax, ca_w1, ca_w2, gate);
    k_pos_reduce<<<BB * LL / 4, 256, 0, stream>>>(x, gate, m, cmax);
    k_scan1<<<112, 256, 0, stream>>>(m, d_wp, d_bp, B_wp, B_bp, A, Pp, Qq);
    k_scan2<<<1, 512, 0, stream>>>(Pp, Qq, hst);
    k_scan3<<<112, 256, 0, stream>>>(m, hst, d_wp, d_bp, B_wp, B_bp, C_wp, C_bp, A, sy);
    k_lsa<<<dim3(BB, HH), 64, 0, stream>>>(m, cmax, lsa_w, ssg);
    k_bnstat<<<dim3(BB, NSL), 256, 0, stream>>>(x, gate, sy, ssg, pb);
    k_bnred<<<512, 256, 0, stream>>>(pb, bnsum, bnsq);
    k_bnfin<<<1, 256, 0, stream>>>(bnsum, bnsq, bn_g, bn_b, scv, shv);
    k_final<<<4096, 256, 0, stream>>>(x, gate, sy, ssg, scv, shv, out);
}